// Round 10
// baseline (526.690 us; speedup 1.0000x reference)
//
#include <hip/hip_runtime.h>
#include <hip/hip_fp16.h>

typedef unsigned int uint32;
typedef _Float16 f16;
typedef f16 f16x4 __attribute__((ext_vector_type(4)));
typedef f16 f16x8 __attribute__((ext_vector_type(8)));
typedef float f32x4 __attribute__((ext_vector_type(4)));

union U8 { f16x8 v; uint4 u4; uint2 u2[2]; f16 h[8]; };

__device__ __forceinline__ float h2f(__half v) { return __half2float(v); }
__device__ __forceinline__ __half f2h(float v) { return __float2half(v); }

// ---------------------------------------------------------------------------
// K0_w1: conv1_w -> W1T[48][192] f16, n-major, zero-padded.
// ---------------------------------------------------------------------------
__global__ __launch_bounds__(256) void k0_w1(const float* __restrict__ W1,
                                             f16* __restrict__ W1T) {
  int i = blockIdx.x * 256 + threadIdx.x;
  if (i < 9216) {
    int n = i / 192, k = i % 192;
    W1T[i] = (n < 36 && k < 180) ? (f16)W1[k * 36 + n] : (f16)0;
  }
}

// ---------------------------------------------------------------------------
// K1 (MFMA, no LDS, no barriers): t1 = leaky_relu(x @ conv1_w + b1), f16 out.
// ---------------------------------------------------------------------------
__global__ __launch_bounds__(256) void k1_conv1(const float* __restrict__ X,
                                                const f16* __restrict__ W1T,
                                                const float* __restrict__ B1,
                                                __half* __restrict__ T1) {
  int t = threadIdx.x;
  int p0 = blockIdx.x * 128;
  int lane = t & 63, wave = t >> 6;
  int lm = lane & 15, lq = lane >> 4;

  f16x8 ax[6][2];
#pragma unroll
  for (int mt = 0; mt < 2; ++mt) {
    int row = p0 + wave * 32 + mt * 16 + lm;
    const float* xr = X + (size_t)row * 180;
#pragma unroll
    for (int ch = 0; ch < 6; ++ch) {
      int k0 = ch * 32 + lq * 8;
      U8 v; v.u4 = (uint4){0u, 0u, 0u, 0u};
      if (k0 + 8 <= 180) {
        float4 a = *(const float4*)&xr[k0];
        float4 b = *(const float4*)&xr[k0 + 4];
        v.h[0]=(f16)a.x; v.h[1]=(f16)a.y; v.h[2]=(f16)a.z; v.h[3]=(f16)a.w;
        v.h[4]=(f16)b.x; v.h[5]=(f16)b.y; v.h[6]=(f16)b.z; v.h[7]=(f16)b.w;
      } else if (k0 < 180) {  // k0 == 176
        float4 a = *(const float4*)&xr[k0];
        v.h[0]=(f16)a.x; v.h[1]=(f16)a.y; v.h[2]=(f16)a.z; v.h[3]=(f16)a.w;
      }
      ax[ch][mt] = v.v;
    }
  }

  f32x4 acc[2][3];
#pragma unroll
  for (int mt = 0; mt < 2; ++mt)
#pragma unroll
    for (int nt = 0; nt < 3; ++nt) acc[mt][nt] = (f32x4){0.f, 0.f, 0.f, 0.f};

#pragma unroll
  for (int ch = 0; ch < 6; ++ch) {
#pragma unroll
    for (int nt = 0; nt < 3; ++nt) {
      int n = nt * 16 + lm;   // < 48, rows >=36 are zeros
      f16x8 bf = *(const f16x8*)&W1T[n * 192 + ch * 32 + lq * 8];
      acc[0][nt] = __builtin_amdgcn_mfma_f32_16x16x32_f16(
          ax[ch][0], bf, acc[0][nt], 0, 0, 0);
      acc[1][nt] = __builtin_amdgcn_mfma_f32_16x16x32_f16(
          ax[ch][1], bf, acc[1][nt], 0, 0, 0);
    }
  }

  float bb[3];
#pragma unroll
  for (int nt = 0; nt < 3; ++nt) {
    int co = nt * 16 + lm;
    bb[nt] = (co < 36) ? B1[co] : 0.f;
  }
#pragma unroll
  for (int mt = 0; mt < 2; ++mt) {
#pragma unroll
    for (int reg = 0; reg < 4; ++reg) {
      int p = p0 + wave * 32 + mt * 16 + lq * 4 + reg;
      __half* o = T1 + (size_t)p * 36;
#pragma unroll
      for (int nt = 0; nt < 3; ++nt) {
        int co = nt * 16 + lm;
        if (co < 36) {
          float v = acc[mt][nt][reg] + bb[nt];
          o[co] = f2h(v > 0.f ? v : 0.2f * v);
        }
      }
    }
  }
}

// ---------------------------------------------------------------------------
// K0_w2: conv2_w -> W2T[9][48][40] f16, n-major per tap, zero-padded.
// ---------------------------------------------------------------------------
__global__ __launch_bounds__(256) void k0_w2(const float* __restrict__ W2,
                                             f16* __restrict__ W2T) {
  int i = blockIdx.x * 256 + threadIdx.x;
  if (i < 17280) {
    int tap = i / 1920, rem = i % 1920, n = rem / 40, k = rem % 40;
    W2T[i] = (n < 36 && k < 36) ? (f16)W2[(tap * 36 + k) * 36 + n] : (f16)0;
  }
}

// ---------------------------------------------------------------------------
// K2 (MFMA implicit GEMM): t2 = leaky_relu(conv3x3(t1)+b2).
// ---------------------------------------------------------------------------
__global__ __launch_bounds__(256) void k2_conv2(const __half* __restrict__ T1,
                                                const f16* __restrict__ W2T,
                                                const float* __restrict__ B2,
                                                __half* __restrict__ T2) {
  __shared__ __align__(16) f16 ins[3 * 132 * 40];  // [kh][xx][ci40]
  int t = threadIdx.x;
  int p0 = blockIdx.x * 128;
  int b = p0 >> 16, y = (p0 >> 8) & 255, x0 = p0 & 255;

  const uint32* T1u = (const uint32*)T1;   // rows are 18 u32
  uint32* insu = (uint32*)ins;             // [kh][xx][20 u32]
  for (int i = t; i < 7920; i += 256) {    // 3*132*20
    int kh = i / 2640, rem = i % 2640;
    int xx = rem / 20, u = rem % 20;
    int ry = y + kh - 1, gx = x0 + xx - 1;
    uint32 v = 0u;
    if (u < 18 && xx < 130 && (unsigned)ry < 256u && (unsigned)gx < 256u)
      v = T1u[((size_t)((b * 256 + ry) * 256 + gx)) * 18 + u];
    insu[i] = v;                           // i == (kh*132+xx)*20+u
  }
  __syncthreads();

  int lane = t & 63, wave = t >> 6;
  int lm = lane & 15, lq = lane >> 4;
  const f16x8 zero8 = {(f16)0,(f16)0,(f16)0,(f16)0,(f16)0,(f16)0,(f16)0,(f16)0};

  f32x4 acc[2][3];
#pragma unroll
  for (int mt = 0; mt < 2; ++mt)
#pragma unroll
    for (int nt = 0; nt < 3; ++nt) acc[mt][nt] = (f32x4){0.f, 0.f, 0.f, 0.f};

#pragma unroll
  for (int kh = 0; kh < 3; ++kh) {
#pragma unroll
    for (int kw = 0; kw < 3; ++kw) {
      int tap = kh * 3 + kw;
      f16x8 a0[2], a1[2];
#pragma unroll
      for (int mt = 0; mt < 2; ++mt) {
        int xx = wave * 32 + mt * 16 + lm + kw;   // <= 129
        const f16* ar = &ins[(kh * 132 + xx) * 40];
        a0[mt] = *(const f16x8*)&ar[lq * 8];
        a1[mt] = (lq == 0) ? *(const f16x8*)&ar[32] : zero8;
      }
#pragma unroll
      for (int nt = 0; nt < 3; ++nt) {
        const f16* br = &W2T[(tap * 48 + nt * 16 + lm) * 40];
        f16x8 b0 = *(const f16x8*)&br[lq * 8];
        f16x8 b1 = (lq == 0) ? *(const f16x8*)&br[32] : zero8;
#pragma unroll
        for (int mt = 0; mt < 2; ++mt) {
          acc[mt][nt] = __builtin_amdgcn_mfma_f32_16x16x32_f16(
              a0[mt], b0, acc[mt][nt], 0, 0, 0);
          acc[mt][nt] = __builtin_amdgcn_mfma_f32_16x16x32_f16(
              a1[mt], b1, acc[mt][nt], 0, 0, 0);
        }
      }
    }
  }

  float bb[3];
#pragma unroll
  for (int nt = 0; nt < 3; ++nt) {
    int co = nt * 16 + lm;
    bb[nt] = (co < 36) ? B2[co] : 0.f;
  }
#pragma unroll
  for (int mt = 0; mt < 2; ++mt) {
#pragma unroll
    for (int reg = 0; reg < 4; ++reg) {
      int p = p0 + wave * 32 + mt * 16 + lq * 4 + reg;
      __half* o = T2 + (size_t)p * 36;
#pragma unroll
      for (int nt = 0; nt < 3; ++nt) {
        int co = nt * 16 + lm;
        if (co < 36) {
          float v = acc[mt][nt][reg] + bb[nt];
          o[co] = f2h(v > 0.f ? v : 0.2f * v);
        }
      }
    }
  }
}

// ---------------------------------------------------------------------------
// K0_wt: transpose+convert W3/WD to n-major f16 tables with zero padding.
// ---------------------------------------------------------------------------
__global__ __launch_bounds__(256) void k0_wt(const float* __restrict__ SW3,
                                             const float* __restrict__ SWD,
                                             f16* __restrict__ WT3,
                                             f16* __restrict__ WTD) {
  int tid = blockIdx.x * 256 + threadIdx.x;
  int stride = gridDim.x * 256;
  for (int i = tid; i < 192 * 40; i += stride) {
    int n = i / 40, k = i % 40;
    WT3[i] = (n < 180 && k < 36) ? (f16)SW3[k * 180 + n] : (f16)0;
  }
  for (int i = tid; i < 192 * 192; i += stride) {
    int n = i / 192, k = i % 192;
    WTD[i] = (n < 180 && k < 180) ? (f16)SWD[k * 180 + n] : (f16)0;
  }
}

// K0_pw: same for proj_w -> PWT[192][192]. Launched AFTER k3 (lives over T2).
__global__ __launch_bounds__(256) void k0_pw(const float* __restrict__ SPW,
                                             f16* __restrict__ PWT) {
  int tid = blockIdx.x * 256 + threadIdx.x;
  int stride = gridDim.x * 256;
  for (int i = tid; i < 192 * 192; i += stride) {
    int n = i / 192, k = i % 192;
    PWT[i] = (n < 180 && k < 180) ? (f16)SPW[k * 180 + n] : (f16)0;
  }
}

// ---------------------------------------------------------------------------
// K3 (MFMA): qv = (t2@W3+b3)*(x@WD+bd), x64 f16, windowed scatter.
// Epilogue repacks each wave's 32x48 C-quadrant through wave-private LDS,
// then stores coalesced 8B uint2 chunks.
// ---------------------------------------------------------------------------
__global__ __launch_bounds__(256) void k3_qv(const float* __restrict__ X,
                                             const __half* __restrict__ T2,
                                             const f16* __restrict__ WT3,
                                             const f16* __restrict__ WTD,
                                             const float* __restrict__ B3,
                                             const float* __restrict__ BD,
                                             __half* __restrict__ QX) {
  __shared__ __align__(16) f16 eplds[4 * 32 * 56];  // wave-private 32x56
  int t = threadIdx.x;
  int p0 = blockIdx.x * 128;
  int lane = t & 63, wave = t >> 6;
  int lm = lane & 15, lq = lane >> 4;

  const f16x8 zero8 = {(f16)0,(f16)0,(f16)0,(f16)0,(f16)0,(f16)0,(f16)0,(f16)0};

  f16x8 ax[6][2];
  f16x8 at0[2];
  f16x8 at1[2];
#pragma unroll
  for (int mt = 0; mt < 2; ++mt) {
    int row = p0 + wave * 32 + mt * 16 + lm;
    const float* xr = X + (size_t)row * 180;
#pragma unroll
    for (int ch = 0; ch < 6; ++ch) {
      int k0 = ch * 32 + lq * 8;
      U8 v; v.u4 = (uint4){0u, 0u, 0u, 0u};
      if (k0 + 8 <= 180) {
        float4 a = *(const float4*)&xr[k0];
        float4 b = *(const float4*)&xr[k0 + 4];
        v.h[0]=(f16)a.x; v.h[1]=(f16)a.y; v.h[2]=(f16)a.z; v.h[3]=(f16)a.w;
        v.h[4]=(f16)b.x; v.h[5]=(f16)b.y; v.h[6]=(f16)b.z; v.h[7]=(f16)b.w;
      } else if (k0 < 180) {  // k0 == 176
        float4 a = *(const float4*)&xr[k0];
        v.h[0]=(f16)a.x; v.h[1]=(f16)a.y; v.h[2]=(f16)a.z; v.h[3]=(f16)a.w;
      }
      ax[ch][mt] = v.v;
    }
    const f16* tr = (const f16*)T2 + (size_t)row * 36;
    U8 tv;
    tv.u2[0] = *(const uint2*)&tr[lq * 8];
    tv.u2[1] = *(const uint2*)&tr[lq * 8 + 4];
    at0[mt] = tv.v;
    U8 t1v; t1v.u4 = (uint4){0u, 0u, 0u, 0u};
    if (lq == 0) t1v.u2[0] = *(const uint2*)&tr[32];
    at1[mt] = t1v.v;
  }

  f16* myl = eplds + wave * 1792;
  for (int bn = 0; bn < 4; ++bn) {
    int n0 = bn * 48;
    f32x4 accC[2][3], accD[2][3];
#pragma unroll
    for (int i = 0; i < 2; ++i)
#pragma unroll
      for (int j = 0; j < 3; ++j) {
        accC[i][j] = (f32x4){0.f, 0.f, 0.f, 0.f};
        accD[i][j] = (f32x4){0.f, 0.f, 0.f, 0.f};
      }

#pragma unroll
    for (int nt = 0; nt < 3; ++nt) {
      int n = n0 + nt * 16 + lm;
      f16x8 b0 = *(const f16x8*)&WT3[n * 40 + lq * 8];
      f16x8 b1 = (lq == 0) ? *(const f16x8*)&WT3[n * 40 + 32] : zero8;
#pragma unroll
      for (int mt = 0; mt < 2; ++mt) {
        accC[mt][nt] = __builtin_amdgcn_mfma_f32_16x16x32_f16(
            at0[mt], b0, accC[mt][nt], 0, 0, 0);
        accC[mt][nt] = __builtin_amdgcn_mfma_f32_16x16x32_f16(
            at1[mt], b1, accC[mt][nt], 0, 0, 0);
      }
    }

#pragma unroll
    for (int ch = 0; ch < 6; ++ch) {
#pragma unroll
      for (int nt = 0; nt < 3; ++nt) {
        int n = n0 + nt * 16 + lm;
        f16x8 bf = *(const f16x8*)&WTD[n * 192 + ch * 32 + lq * 8];
        accD[0][nt] = __builtin_amdgcn_mfma_f32_16x16x32_f16(
            ax[ch][0], bf, accD[0][nt], 0, 0, 0);
        accD[1][nt] = __builtin_amdgcn_mfma_f32_16x16x32_f16(
            ax[ch][1], bf, accD[1][nt], 0, 0, 0);
      }
    }

    float cb[3], db[3];
#pragma unroll
    for (int nt = 0; nt < 3; ++nt) {
      int col = n0 + nt * 16 + lm;
      cb[nt] = (col < 180) ? B3[col] : 0.f;
      db[nt] = (col < 180) ? BD[col] : 0.f;
    }
    // ---- repack through wave-private LDS ----
#pragma unroll
    for (int mt = 0; mt < 2; ++mt)
#pragma unroll
      for (int reg = 0; reg < 4; ++reg) {
        int r = mt * 16 + lq * 4 + reg;
#pragma unroll
        for (int nt = 0; nt < 3; ++nt)
          myl[r * 56 + nt * 16 + lm] =
              (f16)((accC[mt][nt][reg] + cb[nt]) *
                    (accD[mt][nt][reg] + db[nt]) * 64.f);
      }
    // ---- coalesced 8B stores (4 f16 per chunk) ----
#pragma unroll
    for (int it = 0; it < 6; ++it) {
      int idx = it * 64 + lane;          // 0..383 = 32 rows x 12 chunks
      int r = idx / 12, c4 = idx % 12;
      int col = n0 + c4 * 4;
      if (col < 180) {
        int p = p0 + wave * 32 + r;
        int b = p >> 16, y = (p >> 8) & 255, x = p & 255;
        int wi = (b << 8) | ((y >> 4) << 4) | (x >> 4);
        int l = ((y & 15) << 4) | (x & 15);
        uint2 val = *(const uint2*)&myl[r * 56 + c4 * 4];
        *(uint2*)((f16*)QX + ((size_t)(wi * 256 + l)) * 180 + col) = val;
      }
    }
  }
}

// ---------------------------------------------------------------------------
// K5a: position-bias MLP over 961 grid points -> PTAB[961][6] f32
// ---------------------------------------------------------------------------
__device__ __forceinline__ void ln_relu11(const float* p, const float* g,
                                          const float* b, float* r) {
  float m = 0.f;
#pragma unroll
  for (int j = 0; j < 11; ++j) m += p[j];
  m *= (1.0f / 11.0f);
  float v = 0.f;
#pragma unroll
  for (int j = 0; j < 11; ++j) { float d = p[j] - m; v += d * d; }
  v *= (1.0f / 11.0f);
  float inv = 1.0f / sqrtf(v + 1e-5f);
#pragma unroll
  for (int j = 0; j < 11; ++j) {
    float xn = (p[j] - m) * inv * g[j] + b[j];
    r[j] = fmaxf(xn, 0.f);
  }
}
__device__ __forceinline__ void mm11(const float* r, const float* W,
                                     const float* b, float* o) {
#pragma unroll
  for (int j2 = 0; j2 < 11; ++j2) {
    float s = b[j2];
#pragma unroll
    for (int j = 0; j < 11; ++j) s += r[j] * W[j * 11 + j2];
    o[j2] = s;
  }
}

__global__ __launch_bounds__(256) void k5a_posmlp(
    const float* PPW, const float* PPB,
    const float* LN1G, const float* LN1B, const float* M1W, const float* M1B,
    const float* LN2G, const float* LN2B, const float* M2W, const float* M2B,
    const float* LN3G, const float* LN3B, const float* M3W, const float* M3B,
    float* __restrict__ PTAB) {
  int t = blockIdx.x * 256 + threadIdx.x;
  if (t >= 961) return;
  float g0 = (float)(t / 31) - 15.0f;
  float g1 = (float)(t % 31) - 15.0f;
  float p[11], r[11];
#pragma unroll
  for (int j = 0; j < 11; ++j)
    p[j] = g0 * PPW[j] + g1 * PPW[11 + j] + PPB[j];
  ln_relu11(p, LN1G, LN1B, r);
  mm11(r, M1W, M1B, p);
  ln_relu11(p, LN2G, LN2B, r);
  mm11(r, M2W, M2B, p);
  ln_relu11(p, LN3G, LN3B, r);
#pragma unroll
  for (int h = 0; h < 6; ++h) {
    float s = M3B[h];
#pragma unroll
    for (int j = 0; j < 11; ++j) s += r[j] * M3W[j * 6 + h];
    PTAB[t * 6 + h] = s;
  }
}

// ---------------------------------------------------------------------------
// K5b: RPB[h][l][m] = mean over 2x2 of PTAB[(dr+15)*31+(dc+15)][h]
// ---------------------------------------------------------------------------
__global__ __launch_bounds__(256) void k5b_rpb(const float* __restrict__ PTAB,
                                               float* __restrict__ RPB) {
  int t = blockIdx.x * 256 + threadIdx.x;  // < 98304
  int m = t & 63;
  int l = (t >> 6) & 255;
  int h = t >> 14;
  int mh = m >> 3, mw = m & 7;
  int qr = l >> 4, qc = l & 15;
  float s = 0.f;
#pragma unroll
  for (int rh = 0; rh < 2; ++rh)
#pragma unroll
    for (int rw = 0; rw < 2; ++rw) {
      int dr = qr - (mh * 2 + rh) + 15;
      int dc = qc - (mw * 2 + rw) + 15;
      s += PTAB[(dr * 31 + dc) * 6 + h];
    }
  RPB[t] = 0.25f * s;
}

// ---------------------------------------------------------------------------
// KW (fused k7a+kA+kB, one block per window):
//  phase 1: stage vA[256][104] (kB layout, zeros in pad) + qls[256][90]
//  phase 2: cc scalar (k7a) -> ccs[96][104] f16 x65536 IN LDS (no global CC)
//  phase 3: vp build (kA) + qP[256][104] rebuild from global (overlays qls)
//  phase 4: kA MFMA -> x_sp in place over q-channels (x8192 f16)
//  phase 5: kB MFMA (vA, ccs) -> x_ch in place over v-channels (x8192 f16)
// LDS 153,600 B -> 1 block/CU. Saves 2 launches + CC round-trip + QX rereads.
// ---------------------------------------------------------------------------
__global__ __launch_bounds__(256) void kW_win(__half* __restrict__ QX,
                                              const float* __restrict__ RPB,
                                              const float* __restrict__ SLW,
                                              const float* __restrict__ SLB) {
  __shared__ __align__(16) unsigned char SMW[153600];
  f16* vA  = (f16*)SMW;                    // [256][104] v, zeros 90..103
  f16* QU  = (f16*)(SMW + 53248);          // qls [256][90] -> qP [256][104]
  f16* vpS = (f16*)(SMW + 106496);         // [64][104]
  f16* vpT = (f16*)(SMW + 119808);         // [96][72]
  f16* ccs = (f16*)(SMW + 133632);         // [96][104] cc x65536, pads 0
  int wi = blockIdx.x, t = threadIdx.x;
  __half* QW = QX + (size_t)wi * 46080;
  const uint32* G = (const uint32*)QW;

  // ---- phase 1: stage v (kB layout) + q (compact) ----
  uint32* vAw = (uint32*)vA;
  for (int i = t; i < 12288; i += 256) {   // 256 rows x 48 u32
    int l = i / 48, kk = i % 48;
    vAw[l * 52 + kk] = (kk < 45) ? G[l * 90 + 45 + kk] : 0u;
  }
  uint32* qlw = (uint32*)QU;
  for (int i = t; i < 11520; i += 256) {   // 256 rows x 45 u32
    int l = i / 45, k = i % 45;
    qlw[l * 45 + k] = G[l * 90 + k];
  }
  // zero ccs pads (active region [0..89]x[0..89] written in phase 2)
  for (int i = t; i < 9984; i += 256) {
    int c = i / 104, d = i % 104;
    if (c >= 90 || d >= 90) ccs[i] = (f16)0;
  }
  __syncthreads();

  // ---- phase 2: cc scalar (k7a verbatim, strides qls=90, vA=104) ----
  {
    int c0 = (t % 15) * 6, d0 = (t / 15) * 6;
    if (t < 225) {
      float acc[36];
#pragma unroll
      for (int i = 0; i < 36; ++i) acc[i] = 0.f;
      for (int l = 0; l < 256; ++l) {
        const __half2* qh = (const __half2*)&QU[l * 90 + c0];
        const __half2* vh = (const __half2*)&vA[l * 104 + d0];
        float a[6], b[6];
#pragma unroll
        for (int k = 0; k < 3; ++k) {
          __half2 x = qh[k];
          a[2 * k] = __low2float(x); a[2 * k + 1] = __high2float(x);
          __half2 y = vh[k];
          b[2 * k] = __low2float(y); b[2 * k + 1] = __high2float(y);
        }
#pragma unroll
        for (int i = 0; i < 6; ++i)
#pragma unroll
          for (int j = 0; j < 6; ++j) acc[i * 6 + j] += a[i] * b[j];
      }
      // cc_true = acc/(256*4096); ccs = cc_true*65536 = acc/16
#pragma unroll
      for (int i = 0; i < 6; ++i)
#pragma unroll
        for (int j = 0; j < 6; ++j)
          ccs[(c0 + i) * 104 + d0 + j] = (f16)(acc[i * 6 + j] * 0.0625f);
    }
  }
  __syncthreads();   // ccs done; qls consumed

  // ---- phase 3: vp build (kA, vA stride 104) + qP from global ----
  {
    float w0 = SLW[0], w1 = SLW[1], w2 = SLW[2], w3 = SLW[3];
    float sb = SLB[0];
    for (int e = t; e < 6144; e += 256) {
      int m = e & 63, idx = e >> 6;          // idx = h*16 + c
      int c = idx & 15, h = idx >> 4;
      f16 val = (f16)0;
      if (c < 15) {
        int ch = h * 15 + c;
        int lb = (m >> 3) * 32 + (m & 7) * 2;
        float s = w0 * (float)vA[lb * 104 + ch] + w1 * (float)vA[(lb + 1) * 104 + ch]
                + w2 * (float)vA[(lb + 16) * 104 + ch] + w3 * (float)vA[(lb + 17) * 104 + ch];
        val = (f16)(s * 4.f + sb * 256.f);
      }
      vpS[m * 104 + idx] = val;
      vpT[idx * 72 + m] = val;
    }
    for (int j = t; j < 1536; j += 256) {
      int h = j >> 8, l = j & 255;
      QU[l * 104 + h * 16 + 15] = (f16)0;
    }
    for (int i = t; i < 11520; i += 256) {
      int l = i / 45, k = i % 45;
      union { uint32 w; f16 h[2]; } cv;
      cv.w = G[l * 90 + k];
      int cg0 = 2 * k, cg1 = 2 * k + 1;
      int h0 = cg0 / 15, c0 = cg0 - h0 * 15;
      int h1 = cg1 / 15, c1 = cg1 - h1 * 15;
      QU[l * 104 + h0 * 16 + c0] = cv.h[0];
      QU[l * 104 + h1 * 16 + c1] = cv.h[1];
    }
  }
  __syncthreads();

  int lane = t & 63, w = t >> 6;
  int lm = lane & 15, lq = lane >> 4;

  // ---- phase 4: kA MFMA (verbatim; U -> QU) ----
  {
    const float invA = 1.0f / 960.0f;        // 256 / (15*16384)
    for (int h = 0; h < 6; ++h) {
      f16x4 a1[4], b1[4];
#pragma unroll
      for (int mt = 0; mt < 4; ++mt)
        a1[mt] = *(const f16x4*)&vpS[(mt * 16 + lm) * 104 + h * 16 + lq * 4];
#pragma unroll
      for (int lt = 0; lt < 4; ++lt)
        b1[lt] = *(const f16x4*)&QU[(w * 64 + lt * 16 + lm) * 104 + h * 16 + lq * 4];
      f32x4 acc1[4][4];
#pragma unroll
      for (int mt = 0; mt < 4; ++mt)
#pragma unroll
        for (int lt = 0; lt < 4; ++lt)
          acc1[mt][lt] = __builtin_amdgcn_mfma_f32_16x16x16f16(
              a1[mt], b1[lt], (f32x4){0.f, 0.f, 0.f, 0.f}, 0, 0, 0);
      f16x4 b2[4][4];
#pragma unroll
      for (int lt = 0; lt < 4; ++lt) {
        int l = w * 64 + lt * 16 + lm;
        const float* rp = RPB + ((size_t)(h * 256 + l)) * 64;
#pragma unroll
        for (int mt = 0; mt < 4; ++mt) {
          float4 rv = *(const float4*)&rp[mt * 16 + lq * 4];
          f16x4 bb;
          bb[0] = (f16)(acc1[mt][lt][0] * invA + rv.x * 256.f);
          bb[1] = (f16)(acc1[mt][lt][1] * invA + rv.y * 256.f);
          bb[2] = (f16)(acc1[mt][lt][2] * invA + rv.z * 256.f);
          bb[3] = (f16)(acc1[mt][lt][3] * invA + rv.w * 256.f);
          b2[mt][lt] = bb;
        }
      }
      f16x4 a2[4];
#pragma unroll
      for (int kt = 0; kt < 4; ++kt)
        a2[kt] = *(const f16x4*)&vpT[(h * 16 + lm) * 72 + kt * 16 + lq * 4];
#pragma unroll
      for (int lt = 0; lt < 4; ++lt) {
        f32x4 acc2 = (f32x4){0.f, 0.f, 0.f, 0.f};
#pragma unroll
        for (int kt = 0; kt < 4; ++kt)
          acc2 = __builtin_amdgcn_mfma_f32_16x16x16f16(a2[kt], b2[kt][lt], acc2, 0, 0, 0);
        int l = w * 64 + lt * 16 + lm;
        __half* orow = QW + l * 180 + h * 15;
#pragma unroll
        for (int reg = 0; reg < 4; ++reg) {
          int c = lq * 4 + reg;
          if (c < 15) orow[c] = f2h(acc2[reg] * 0.125f);   // 65536*x_sp / 8
        }
      }
    }
  }
  __syncthreads();   // safety (no LDS hazard: phase 5 reads vA/ccs only)

  // ---- phase 5: kB MFMA (verbatim; ccB -> ccs) ----
  {
    f32x4 acc[4][6];
#pragma unroll
    for (int mt = 0; mt < 4; ++mt)
#pragma unroll
      for (int nt = 0; nt < 6; ++nt) acc[mt][nt] = (f32x4){0.f, 0.f, 0.f, 0.f};
    for (int kc = 0; kc < 3; ++kc) {
      f16x8 af[4], bf[6];
#pragma unroll
      for (int mt = 0; mt < 4; ++mt)
        af[mt] = *(const f16x8*)&vA[(w * 64 + mt * 16 + lm) * 104 + kc * 32 + lq * 8];
#pragma unroll
      for (int nt = 0; nt < 6; ++nt)
        bf[nt] = *(const f16x8*)&ccs[(nt * 16 + lm) * 104 + kc * 32 + lq * 8];
#pragma unroll
      for (int mt = 0; mt < 4; ++mt)
#pragma unroll
        for (int nt = 0; nt < 6; ++nt)
          acc[mt][nt] = __builtin_amdgcn_mfma_f32_16x16x32_f16(
              af[mt], bf[nt], acc[mt][nt], 0, 0, 0);
    }
#pragma unroll
    for (int mt = 0; mt < 4; ++mt) {
#pragma unroll
      for (int reg = 0; reg < 4; ++reg) {
        int l = w * 64 + mt * 16 + lq * 4 + reg;
        __half* orow = QW + l * 180 + 90;
#pragma unroll
        for (int nt = 0; nt < 6; ++nt) {
          int c = nt * 16 + lm;
          if (c < 90) orow[c] = f2h(acc[mt][nt][reg] * 0.001953125f);  // 2^22 -> 2^13
        }
      }
    }
  }
}

// ---------------------------------------------------------------------------
// K8 (MFMA, no LDS, no barriers): out = (XS/8192) @ proj_w + proj_b, f32 out,
// window-reverse scatter.
// ---------------------------------------------------------------------------
__global__ __launch_bounds__(256) void k8_proj(const __half* __restrict__ XS,
                                               const f16* __restrict__ PWT,
                                               const float* __restrict__ PB,
                                               float* __restrict__ OUT) {
  int t = threadIdx.x;
  int w0r = blockIdx.x * 128;
  int lane = t & 63, wave = t >> 6;
  int lm = lane & 15, lq = lane >> 4;

  f16x8 ax[6][2];
#pragma unroll
  for (int mt = 0; mt < 2; ++mt) {
    int row = w0r + wave * 32 + mt * 16 + lm;
    const f16* xr = (const f16*)XS + (size_t)row * 180;
#pragma unroll
    for (int ch = 0; ch < 6; ++ch) {
      int k0 = ch * 32 + lq * 8;
      U8 v; v.u4 = (uint4){0u, 0u, 0u, 0u};
      if (k0 + 8 <= 180) {
        v.u2[0] = *(const uint2*)&xr[k0];
        v.u2[1] = *(const uint2*)&xr[k0 + 4];
      } else if (k0 < 180) {  // k0 == 176
        v.u2[0] = *(const uint2*)&xr[k0];
      }
      ax[ch][mt] = v.v;
    }
  }

  for (int bn = 0; bn < 4; ++bn) {
    int n0 = bn * 48;
    f32x4 acc[2][3];
#pragma unroll
    for (int i = 0; i < 2; ++i)
#pragma unroll
      for (int j = 0; j < 3; ++j) acc[i][j] = (f32x4){0.f, 0.f, 0.f, 0.f};

#pragma unroll
    for (int ch = 0; ch < 6; ++ch) {
#pragma unroll
      for (int nt = 0; nt < 3; ++nt) {
        int n = n0 + nt * 16 + lm;
        f16x8 bf = *(const f16x8*)&PWT[n * 192 + ch * 32 + lq * 8];
        acc[0][nt] = __builtin_amdgcn_mfma_f32_16x16x32_f16(
            ax[ch][0], bf, acc[0][nt], 0, 0, 0);
        acc[1][nt] = __builtin_amdgcn_mfma_f32_16x16x32_f16(
            ax[ch][1], bf, acc[1][nt], 0, 0, 0);
      }
    }

    float pb[3];
#pragma unroll
    for (int nt = 0; nt < 3; ++nt) {
      int col = n0 + nt * 16 + lm;
      pb[nt] = (col < 180) ? PB[col] : 0.f;
    }
    const float inv = 1.0f / 8192.0f;
#pragma unroll
    for (int mt = 0; mt < 2; ++mt) {
#pragma unroll
      for (int reg = 0; reg < 4; ++reg) {
        int w = w0r + wave * 32 + mt * 16 + lq * 4 + reg;
        int wi = w >> 8, l = w & 255;
        int b = wi >> 8, wy = (wi >> 4) & 15, wx = wi & 15;
        int ly = l >> 4, lx = l & 15;
        int p = (b << 16) | (((wy << 4) | ly) << 8) | ((wx << 4) | lx);
        float* orow = OUT + (size_t)p * 180;
#pragma unroll
        for (int nt = 0; nt < 3; ++nt) {
          int col = n0 + nt * 16 + lm;
          if (col < 180) orow[col] = acc[mt][nt][reg] * inv + pb[nt];
        }
      }
    }
  }
}

// ---------------------------------------------------------------------------
// Workspace layout: as round 7, CC no longer used (kept reserved).
// ---------------------------------------------------------------------------
extern "C" void kernel_launch(void* const* d_in, const int* in_sizes, int n_in,
                              void* d_out, int out_size, void* d_ws, size_t ws_size,
                              hipStream_t stream) {
  const float* X    = (const float*)d_in[0];
  const float* W1   = (const float*)d_in[1];
  const float* B1   = (const float*)d_in[2];
  const float* W2   = (const float*)d_in[3];
  const float* B2   = (const float*)d_in[4];
  const float* W3   = (const float*)d_in[5];
  const float* B3c  = (const float*)d_in[6];
  const float* WD   = (const float*)d_in[7];
  const float* BD   = (const float*)d_in[8];
  const float* SLW  = (const float*)d_in[9];
  const float* SLB  = (const float*)d_in[10];
  const float* PPW  = (const float*)d_in[11];
  const float* PPB  = (const float*)d_in[12];
  const float* LN1G = (const float*)d_in[13];
  const float* LN1B = (const float*)d_in[14];
  const float* M1W  = (const float*)d_in[15];
  const float* M1B  = (const float*)d_in[16];
  const float* LN2G = (const float*)d_in[17];
  const float* LN2B = (const float*)d_in[18];
  const float* M2W  = (const float*)d_in[19];
  const float* M2B  = (const float*)d_in[20];
  const float* LN3G = (const float*)d_in[21];
  const float* LN3B = (const float*)d_in[22];
  const float* M3W  = (const float*)d_in[23];
  const float* M3B  = (const float*)d_in[24];
  const float* PW   = (const float*)d_in[25];
  const float* PB   = (const float*)d_in[26];
  float* OUT = (float*)d_out;

  char* ws = (char*)d_ws;
  f16*   W2T  = (f16*)(ws);
  f16*   W1T  = (f16*)(ws + 34560);
  __half* QX  = (__half*)(ws);
  __half* T1  = (__half*)(ws + 47185920);
  __half* T2  = (__half*)(ws + 56623104);
  float* PTAB = (float*)(ws + 47185920);
  float* RPB  = (float*)(ws + 47212544);
  f16*   WT3  = (f16*)(ws + 47605760);
  f16*   WTD  = (f16*)(ws + 47621120);
  f16*   PWT  = (f16*)(ws + 64194560);

  hipLaunchKernelGGL(k0_w2, dim3(68), dim3(256), 0, stream, W2, W2T);
  hipLaunchKernelGGL(k0_w1, dim3(36), dim3(256), 0, stream, W1, W1T);
  hipLaunchKernelGGL(k1_conv1, dim3(1024), dim3(256), 0, stream, X, W1T, B1, T1);
  hipLaunchKernelGGL(k2_conv2, dim3(1024), dim3(256), 0, stream, T1, W2T, B2, T2);
  hipLaunchKernelGGL(k0_wt, dim3(144), dim3(256), 0, stream, W3, WD, WT3, WTD);
  hipLaunchKernelGGL(k3_qv, dim3(1024), dim3(256), 0, stream, X, T2, WT3, WTD, B3c, BD, QX);
  hipLaunchKernelGGL(k0_pw, dim3(144), dim3(256), 0, stream, PW, PWT);
  hipLaunchKernelGGL(k5a_posmlp, dim3(4), dim3(256), 0, stream,
                     PPW, PPB, LN1G, LN1B, M1W, M1B, LN2G, LN2B, M2W, M2B,
                     LN3G, LN3B, M3W, M3B, PTAB);
  hipLaunchKernelGGL(k5b_rpb, dim3(384), dim3(256), 0, stream, PTAB, RPB);
  hipLaunchKernelGGL(kW_win, dim3(512), dim3(256), 0, stream, QX, RPB, SLW, SLB);
  hipLaunchKernelGGL(k8_proj, dim3(1024), dim3(256), 0, stream, QX, PWT, PB, OUT);
}